// Round 1
// baseline (597.213 us; speedup 1.0000x reference)
//
#include <hip/hip_runtime.h>
#include <hip/hip_bf16.h>
#include <math.h>

// Sizes (fixed by the problem)
#define NN 50000
#define EE 800000
#define FIN 256
#define FH 96
#define FC 40

// ---------------- degree / norm ----------------

__global__ void k_init_deg(unsigned* deg, int n) {
    int i = blockIdx.x * blockDim.x + threadIdx.x;
    if (i < n) deg[i] = 1u;  // self-loop contributes 1 to degree
}

__global__ void k_count_deg(const int* __restrict__ row, unsigned* deg, int e) {
    int i = blockIdx.x * blockDim.x + threadIdx.x;
    if (i < e) atomicAdd(&deg[row[i]], 1u);
}

__global__ void k_dinv(unsigned* deg, int n) {
    int i = blockIdx.x * blockDim.x + threadIdx.x;
    if (i < n) {
        unsigned d = deg[i];
        ((float*)deg)[i] = rsqrtf((float)d);
    }
}

__global__ void k_norm(const int* __restrict__ row, const int* __restrict__ col,
                       const float* __restrict__ ew, const float* __restrict__ dinv,
                       float* __restrict__ norm, int e) {
    int i = blockIdx.x * blockDim.x + threadIdx.x;
    if (i < e) norm[i] = dinv[row[i]] * ew[i] * dinv[col[i]];
}

// ---------------- GEMM1: h0 = x @ W1^T   [N,256]x[96,256]^T -> [N,96] ----------------

__global__ __launch_bounds__(256) void k_gemm1(const float* __restrict__ x,
                                               const float* __restrict__ W,
                                               float* __restrict__ h0, int n) {
    __shared__ float xs[32][33];
    __shared__ float ws[96][33];
    int tid = threadIdx.x;
    int row0 = blockIdx.x * 32;
    float acc[12];
#pragma unroll
    for (int c = 0; c < 12; ++c) acc[c] = 0.f;

    for (int k0 = 0; k0 < FIN; k0 += 32) {
#pragma unroll
        for (int j = 0; j < 4; ++j) {
            int i = tid + j * 256;
            int r = i >> 5, k = i & 31;
            int gr = row0 + r;
            xs[r][k] = (gr < n) ? x[gr * FIN + k0 + k] : 0.f;
        }
#pragma unroll
        for (int j = 0; j < 12; ++j) {
            int i = tid + j * 256;
            int c = i >> 5, k = i & 31;
            ws[c][k] = W[c * FIN + k0 + k];
        }
        __syncthreads();
        int r = tid & 31, cg = tid >> 5;
        int cbase = cg * 12;
#pragma unroll
        for (int k = 0; k < 32; ++k) {
            float xv = xs[r][k];
#pragma unroll
            for (int c = 0; c < 12; ++c) acc[c] = fmaf(xv, ws[cbase + c][k], acc[c]);
        }
        __syncthreads();
    }
    int r = tid & 31, cg = tid >> 5;
    int gr = row0 + r;
    if (gr < n) {
#pragma unroll
        for (int c = 0; c < 12; ++c) h0[gr * FH + cg * 12 + c] = acc[c];
    }
}

// ---------------- self-loop init: agg[n][f] = dinv[n]^2 * h[n][f] (float4) ----------------

__global__ void k_self_init96(const float* __restrict__ h0, const float* __restrict__ dinv,
                              float* __restrict__ agg, int n) {
    int j = blockIdx.x * blockDim.x + threadIdx.x;  // over n*24 float4s
    if (j >= n * 24) return;
    int node = j / 24;
    float s = dinv[node]; s = s * s;
    float4 v = ((const float4*)h0)[j];
    v.x *= s; v.y *= s; v.z *= s; v.w *= s;
    ((float4*)agg)[j] = v;
}

__global__ void k_self_init40(const float* __restrict__ h1, const float* __restrict__ dinv,
                              float* __restrict__ agg, int n) {
    int j = blockIdx.x * blockDim.x + threadIdx.x;  // over n*10 float4s
    if (j >= n * 10) return;
    int node = j / 10;
    float s = dinv[node]; s = s * s;
    float4 v = ((const float4*)h1)[j];
    v.x *= s; v.y *= s; v.z *= s; v.w *= s;
    ((float4*)agg)[j] = v;
}

// ---------------- edge scatter (atomics) ----------------

__global__ void k_scatter96(const int* __restrict__ row, const int* __restrict__ col,
                            const float* __restrict__ norm, const float* __restrict__ h0,
                            float* __restrict__ agg, int total) {
    int tid = blockIdx.x * blockDim.x + threadIdx.x;
    if (tid >= total) return;
    int e = tid / FH;
    int f = tid - e * FH;
    float v = norm[e] * h0[row[e] * FH + f];
    atomicAdd(&agg[col[e] * FH + f], v);
}

__global__ void k_scatter40(const int* __restrict__ row, const int* __restrict__ col,
                            const float* __restrict__ norm, const float* __restrict__ h1,
                            float* __restrict__ agg, int total) {
    int tid = blockIdx.x * blockDim.x + threadIdx.x;
    if (tid >= total) return;
    int e = tid / FC;
    int f = tid - e * FC;
    float v = norm[e] * h1[row[e] * FC + f];
    atomicAdd(&agg[col[e] * FC + f], v);
}

// ---------------- bias + relu (in place on agg1) ----------------

__global__ void k_bias_relu(float* __restrict__ agg, const float* __restrict__ b, int n) {
    int j = blockIdx.x * blockDim.x + threadIdx.x;  // over n*24 float4s
    if (j >= n * 24) return;
    int fb = (j % 24);
    float4 bv = ((const float4*)b)[fb];
    float4 v = ((float4*)agg)[j];
    v.x = fmaxf(v.x + bv.x, 0.f);
    v.y = fmaxf(v.y + bv.y, 0.f);
    v.z = fmaxf(v.z + bv.z, 0.f);
    v.w = fmaxf(v.w + bv.w, 0.f);
    ((float4*)agg)[j] = v;
}

// ---------------- GEMM2: h1 = h @ W2^T  [N,96]x[40,96]^T -> [N,40] ----------------

__global__ __launch_bounds__(256) void k_gemm2(const float* __restrict__ h,
                                               const float* __restrict__ W,
                                               float* __restrict__ h1, int n) {
    __shared__ float hs[64][97];
    __shared__ float w2s[40][97];
    int tid = threadIdx.x;
    int row0 = blockIdx.x * 64;

    // load h tile: 64x96
#pragma unroll
    for (int j = 0; j < 24; ++j) {
        int i = tid + j * 256;
        int r = i / 96, k = i - r * 96;
        int gr = row0 + r;
        hs[r][k] = (gr < n) ? h[gr * FH + k] : 0.f;
    }
    // load W2: 40x96
#pragma unroll
    for (int j = 0; j < 15; ++j) {
        int i = tid + j * 256;
        int c = i / 96, k = i - c * 96;
        w2s[c][k] = W[c * FH + k];
    }
    __syncthreads();

    int r = tid >> 2, og = tid & 3;  // r 0..63, og 0..3 -> 10 outputs each
    float acc[10];
#pragma unroll
    for (int c = 0; c < 10; ++c) acc[c] = 0.f;
#pragma unroll 4
    for (int k = 0; k < FH; ++k) {
        float hv = hs[r][k];
#pragma unroll
        for (int c = 0; c < 10; ++c) acc[c] = fmaf(hv, w2s[og * 10 + c][k], acc[c]);
    }
    int gr = row0 + r;
    if (gr < n) {
#pragma unroll
        for (int c = 0; c < 10; ++c) h1[gr * FC + og * 10 + c] = acc[c];
    }
}

// ---------------- bias + log_softmax (wave per row) ----------------

__global__ void k_lsm(float* __restrict__ out, const float* __restrict__ b, int n) {
    int gtid = blockIdx.x * blockDim.x + threadIdx.x;
    int wid = gtid >> 6;
    int lane = threadIdx.x & 63;
    if (wid >= n) return;
    float vv = 0.f, v = -INFINITY;
    if (lane < FC) {
        vv = out[wid * FC + lane] + b[lane];
        v = vv;
    }
#pragma unroll
    for (int o = 32; o; o >>= 1) v = fmaxf(v, __shfl_xor(v, o));
    float ex = (lane < FC) ? expf(vv - v) : 0.f;
#pragma unroll
    for (int o = 32; o; o >>= 1) ex += __shfl_xor(ex, o);
    float lse = logf(ex) + v;
    if (lane < FC) out[wid * FC + lane] = vv - lse;
}

// ---------------- launch ----------------

extern "C" void kernel_launch(void* const* d_in, const int* in_sizes, int n_in,
                              void* d_out, int out_size, void* d_ws, size_t ws_size,
                              hipStream_t stream) {
    const float* x  = (const float*)d_in[0];
    const int*   ei = (const int*)d_in[1];
    const float* ew = (const float*)d_in[2];
    const float* W1 = (const float*)d_in[3];
    const float* b1 = (const float*)d_in[4];
    const float* W2 = (const float*)d_in[5];
    const float* b2 = (const float*)d_in[6];
    float* out = (float*)d_out;

    const int N = NN;
    const int E = in_sizes[1] / 2;  // 800000
    const int* row = ei;
    const int* col = ei + E;

    float* ws = (float*)d_ws;
    // layout (floats)
    float*    dinv = ws;                       // N (first used as unsigned deg)
    unsigned* deg  = (unsigned*)ws;
    float* norm = ws + 50176;                  // E
    float* h0   = ws + 850176;                 // N*96
    float* agg1 = ws + 5650176;                // N*96 (then becomes h after relu)
    float* h1   = ws + 10450176;               // N*40

    const int B = 256;

    hipLaunchKernelGGL(k_init_deg, dim3((N + B - 1) / B), dim3(B), 0, stream, deg, N);
    hipLaunchKernelGGL(k_count_deg, dim3((E + B - 1) / B), dim3(B), 0, stream, row, deg, E);
    hipLaunchKernelGGL(k_dinv, dim3((N + B - 1) / B), dim3(B), 0, stream, deg, N);
    hipLaunchKernelGGL(k_norm, dim3((E + B - 1) / B), dim3(B), 0, stream, row, col, ew, dinv, norm, E);

    hipLaunchKernelGGL(k_gemm1, dim3((N + 31) / 32), dim3(B), 0, stream, x, W1, h0, N);

    hipLaunchKernelGGL(k_self_init96, dim3((N * 24 + B - 1) / B), dim3(B), 0, stream, h0, dinv, agg1, N);
    {
        int total = E * FH;
        hipLaunchKernelGGL(k_scatter96, dim3((total + B - 1) / B), dim3(B), 0, stream, row, col, norm, h0, agg1, total);
    }
    hipLaunchKernelGGL(k_bias_relu, dim3((N * 24 + B - 1) / B), dim3(B), 0, stream, agg1, b1, N);

    hipLaunchKernelGGL(k_gemm2, dim3((N + 63) / 64), dim3(B), 0, stream, agg1, W2, h1, N);

    hipLaunchKernelGGL(k_self_init40, dim3((N * 10 + B - 1) / B), dim3(B), 0, stream, h1, dinv, out, N);
    {
        int total = E * FC;
        hipLaunchKernelGGL(k_scatter40, dim3((total + B - 1) / B), dim3(B), 0, stream, row, col, norm, h1, out, total);
    }
    hipLaunchKernelGGL(k_lsm, dim3((N * 64 + B - 1) / B), dim3(B), 0, stream, out, b2, N);
}

// Round 2
// 344.552 us; speedup vs baseline: 1.7333x; 1.7333x over previous
//
#include <hip/hip_runtime.h>
#include <hip/hip_bf16.h>
#include <math.h>

#define NN 50000
#define EE 800000
#define FIN 256
#define FH 96
#define FC 40

// ---------------- init: deg=1 (self loop), cnt=0 ----------------

__global__ void k_init(unsigned* __restrict__ deg, unsigned* __restrict__ cnt, int n) {
    int i = blockIdx.x * blockDim.x + threadIdx.x;
    if (i < n) { deg[i] = 1u; cnt[i] = 0u; }
}

// ---------------- count out-degree (row) and in-count (col) ----------------

__global__ void k_count(const int* __restrict__ row, const int* __restrict__ col,
                        unsigned* __restrict__ deg, unsigned* __restrict__ cnt, int e) {
    int i = blockIdx.x * blockDim.x + threadIdx.x;
    if (i < e) {
        atomicAdd(&deg[row[i]], 1u);
        atomicAdd(&cnt[col[i]], 1u);
    }
}

__global__ void k_dinv(unsigned* deg, int n) {
    int i = blockIdx.x * blockDim.x + threadIdx.x;
    if (i < n) {
        unsigned d = deg[i];
        ((float*)deg)[i] = rsqrtf((float)d);
    }
}

// ---------------- exclusive scan of cnt -> off (3 kernels) ----------------

__global__ __launch_bounds__(1024) void k_scanA(const unsigned* __restrict__ cnt,
                                                unsigned* __restrict__ off,
                                                unsigned* __restrict__ bsum, int n) {
    __shared__ unsigned s[1024];
    int t = threadIdx.x;
    int i = blockIdx.x * 1024 + t;
    unsigned v = (i < n) ? cnt[i] : 0u;
    s[t] = v;
    __syncthreads();
    for (int o = 1; o < 1024; o <<= 1) {
        unsigned tv = (t >= o) ? s[t - o] : 0u;
        __syncthreads();
        s[t] += tv;
        __syncthreads();
    }
    if (i < n) off[i] = s[t] - v;  // exclusive
    if (t == 1023) bsum[blockIdx.x] = s[1023];
}

__global__ void k_scanB1(unsigned* bsum, int nb) {
    if (threadIdx.x == 0 && blockIdx.x == 0) {
        unsigned run = 0;
        for (int b = 0; b < nb; ++b) { unsigned tv = bsum[b]; bsum[b] = run; run += tv; }
    }
}

__global__ void k_scanB2(unsigned* __restrict__ off, const unsigned* __restrict__ bsum,
                         unsigned* __restrict__ cursor, int n, unsigned e) {
    int i = blockIdx.x * blockDim.x + threadIdx.x;
    if (i < n) {
        unsigned v = off[i] + bsum[i >> 10];
        off[i] = v;
        cursor[i] = v;
    }
    if (i == n) off[n] = e;
}

// ---------------- bucket-scatter edges into CSR (packed {row, norm}) ----------------

__global__ void k_csr(const int* __restrict__ row, const int* __restrict__ col,
                      const float* __restrict__ ew, const float* __restrict__ dinv,
                      unsigned* __restrict__ cursor, float2* __restrict__ epk, int e) {
    int i = blockIdx.x * blockDim.x + threadIdx.x;
    if (i >= e) return;
    int r = row[i], c = col[i];
    unsigned pos = atomicAdd(&cursor[c], 1u);
    float2 p;
    p.x = __int_as_float(r);
    p.y = dinv[r] * ew[i] * dinv[c];
    epk[pos] = p;
}

// ---------------- GEMM1: h0 = x @ W1^T   [N,256]x[96,256]^T -> [N,96] ----------------

__global__ __launch_bounds__(256) void k_gemm1(const float* __restrict__ x,
                                               const float* __restrict__ W,
                                               float* __restrict__ h0, int n) {
    __shared__ float xs[32][33];
    __shared__ float ws[96][33];
    int tid = threadIdx.x;
    int row0 = blockIdx.x * 32;
    float acc[12];
#pragma unroll
    for (int c = 0; c < 12; ++c) acc[c] = 0.f;

    for (int k0 = 0; k0 < FIN; k0 += 32) {
#pragma unroll
        for (int j = 0; j < 4; ++j) {
            int i = tid + j * 256;
            int r = i >> 5, k = i & 31;
            int gr = row0 + r;
            xs[r][k] = (gr < n) ? x[gr * FIN + k0 + k] : 0.f;
        }
#pragma unroll
        for (int j = 0; j < 12; ++j) {
            int i = tid + j * 256;
            int c = i >> 5, k = i & 31;
            ws[c][k] = W[c * FIN + k0 + k];
        }
        __syncthreads();
        int r = tid & 31, cg = tid >> 5;
        int cbase = cg * 12;
#pragma unroll
        for (int k = 0; k < 32; ++k) {
            float xv = xs[r][k];
#pragma unroll
            for (int c = 0; c < 12; ++c) acc[c] = fmaf(xv, ws[cbase + c][k], acc[c]);
        }
        __syncthreads();
    }
    int r = tid & 31, cg = tid >> 5;
    int gr = row0 + r;
    if (gr < n) {
#pragma unroll
        for (int c = 0; c < 12; ++c) h0[gr * FH + cg * 12 + c] = acc[c];
    }
}

// ---------------- aggregation 96: h = relu(A_norm @ h0 + b1) ----------------

__global__ __launch_bounds__(256) void k_agg96(const float* __restrict__ h0,
                                               const unsigned* __restrict__ off,
                                               const float2* __restrict__ epk,
                                               const float* __restrict__ dinv,
                                               const float* __restrict__ b,
                                               float* __restrict__ outh, int n) {
    int tid = blockIdx.x * 256 + threadIdx.x;
    int node = tid / 24;
    int f4 = tid - node * 24;
    if (node >= n) return;
    float s = dinv[node]; s = s * s;
    float4 acc = ((const float4*)h0)[node * 24 + f4];
    acc.x *= s; acc.y *= s; acc.z *= s; acc.w *= s;
    unsigned st = off[node], en = off[node + 1];
    for (unsigned e = st; e < en; ++e) {
        float2 p = epk[e];
        int r = __float_as_int(p.x);
        float nr = p.y;
        float4 v = ((const float4*)h0)[r * 24 + f4];
        acc.x = fmaf(nr, v.x, acc.x);
        acc.y = fmaf(nr, v.y, acc.y);
        acc.z = fmaf(nr, v.z, acc.z);
        acc.w = fmaf(nr, v.w, acc.w);
    }
    float4 bv = ((const float4*)b)[f4];
    acc.x = fmaxf(acc.x + bv.x, 0.f);
    acc.y = fmaxf(acc.y + bv.y, 0.f);
    acc.z = fmaxf(acc.z + bv.z, 0.f);
    acc.w = fmaxf(acc.w + bv.w, 0.f);
    ((float4*)outh)[node * 24 + f4] = acc;
}

// ---------------- GEMM2: h1 = h @ W2^T  [N,96]x[40,96]^T -> [N,40] ----------------

__global__ __launch_bounds__(256) void k_gemm2(const float* __restrict__ h,
                                               const float* __restrict__ W,
                                               float* __restrict__ h1, int n) {
    __shared__ float hs[64][97];
    __shared__ float w2s[40][97];
    int tid = threadIdx.x;
    int row0 = blockIdx.x * 64;

#pragma unroll
    for (int j = 0; j < 24; ++j) {
        int i = tid + j * 256;
        int r = i / 96, k = i - r * 96;
        int gr = row0 + r;
        hs[r][k] = (gr < n) ? h[gr * FH + k] : 0.f;
    }
#pragma unroll
    for (int j = 0; j < 15; ++j) {
        int i = tid + j * 256;
        int c = i / 96, k = i - c * 96;
        w2s[c][k] = W[c * FH + k];
    }
    __syncthreads();

    int r = tid >> 2, og = tid & 3;
    float acc[10];
#pragma unroll
    for (int c = 0; c < 10; ++c) acc[c] = 0.f;
#pragma unroll 4
    for (int k = 0; k < FH; ++k) {
        float hv = hs[r][k];
#pragma unroll
        for (int c = 0; c < 10; ++c) acc[c] = fmaf(hv, w2s[og * 10 + c][k], acc[c]);
    }
    int gr = row0 + r;
    if (gr < n) {
#pragma unroll
        for (int c = 0; c < 10; ++c) h1[gr * FC + og * 10 + c] = acc[c];
    }
}

// ---------------- aggregation 40: out = A_norm @ h1 + b2 ----------------

__global__ __launch_bounds__(256) void k_agg40(const float* __restrict__ h1,
                                               const unsigned* __restrict__ off,
                                               const float2* __restrict__ epk,
                                               const float* __restrict__ dinv,
                                               const float* __restrict__ b,
                                               float* __restrict__ out, int n) {
    int tid = blockIdx.x * 256 + threadIdx.x;
    int node = tid / 10;
    int f4 = tid - node * 10;
    if (node >= n) return;
    float s = dinv[node]; s = s * s;
    float4 acc = ((const float4*)h1)[node * 10 + f4];
    acc.x *= s; acc.y *= s; acc.z *= s; acc.w *= s;
    unsigned st = off[node], en = off[node + 1];
    for (unsigned e = st; e < en; ++e) {
        float2 p = epk[e];
        int r = __float_as_int(p.x);
        float nr = p.y;
        float4 v = ((const float4*)h1)[r * 10 + f4];
        acc.x = fmaf(nr, v.x, acc.x);
        acc.y = fmaf(nr, v.y, acc.y);
        acc.z = fmaf(nr, v.z, acc.z);
        acc.w = fmaf(nr, v.w, acc.w);
    }
    float4 bv = ((const float4*)b)[f4];
    acc.x += bv.x; acc.y += bv.y; acc.z += bv.z; acc.w += bv.w;
    ((float4*)out)[node * 10 + f4] = acc;
}

// ---------------- log_softmax (wave per row, bias already applied) ----------------

__global__ void k_lsm(float* __restrict__ out, int n) {
    int gtid = blockIdx.x * blockDim.x + threadIdx.x;
    int wid = gtid >> 6;
    int lane = threadIdx.x & 63;
    if (wid >= n) return;
    float vv = 0.f, v = -INFINITY;
    if (lane < FC) {
        vv = out[wid * FC + lane];
        v = vv;
    }
#pragma unroll
    for (int o = 32; o; o >>= 1) v = fmaxf(v, __shfl_xor(v, o));
    float ex = (lane < FC) ? expf(vv - v) : 0.f;
#pragma unroll
    for (int o = 32; o; o >>= 1) ex += __shfl_xor(ex, o);
    float lse = logf(ex) + v;
    if (lane < FC) out[wid * FC + lane] = vv - lse;
}

// ---------------- launch ----------------

extern "C" void kernel_launch(void* const* d_in, const int* in_sizes, int n_in,
                              void* d_out, int out_size, void* d_ws, size_t ws_size,
                              hipStream_t stream) {
    const float* x  = (const float*)d_in[0];
    const int*   ei = (const int*)d_in[1];
    const float* ew = (const float*)d_in[2];
    const float* W1 = (const float*)d_in[3];
    const float* b1 = (const float*)d_in[4];
    const float* W2 = (const float*)d_in[5];
    const float* b2 = (const float*)d_in[6];
    float* out = (float*)d_out;

    const int N = NN;
    const int E = in_sizes[1] / 2;
    const int* row = ei;
    const int* col = ei + E;

    float* ws = (float*)d_ws;
    // workspace layout (4-byte units)
    unsigned* deg    = (unsigned*)(ws + 0);        // N  (becomes dinv float)
    float*    dinv   = (float*)deg;
    unsigned* cnt    = (unsigned*)(ws + 50176);    // N  (becomes cursor)
    unsigned* cursor = cnt;
    unsigned* off    = (unsigned*)(ws + 100352);   // N+1
    unsigned* bsum   = (unsigned*)(ws + 150656);   // 64
    float2*   epk    = (float2*)(ws + 150784);     // 2*E
    float*    h0     = ws + 1750784;               // N*96 (later reused as h1: N*40)
    float*    h1     = h0;
    float*    h      = ws + 6550784;               // N*96
    // total = 11,350,784 floats = 45.4 MB

    const int B = 256;
    const int NB_SCAN = (N + 1023) / 1024;

    hipLaunchKernelGGL(k_init, dim3((N + B - 1) / B), dim3(B), 0, stream, deg, cnt, N);
    hipLaunchKernelGGL(k_count, dim3((E + B - 1) / B), dim3(B), 0, stream, row, col, deg, cnt, E);
    hipLaunchKernelGGL(k_dinv, dim3((N + B - 1) / B), dim3(B), 0, stream, deg, N);

    hipLaunchKernelGGL(k_scanA, dim3(NB_SCAN), dim3(1024), 0, stream, cnt, off, bsum, N);
    hipLaunchKernelGGL(k_scanB1, dim3(1), dim3(64), 0, stream, bsum, NB_SCAN);
    hipLaunchKernelGGL(k_scanB2, dim3((N + 1 + B - 1) / B), dim3(B), 0, stream, off, bsum, cursor, N, (unsigned)E);

    hipLaunchKernelGGL(k_csr, dim3((E + B - 1) / B), dim3(B), 0, stream, row, col, ew, dinv, cursor, epk, E);

    hipLaunchKernelGGL(k_gemm1, dim3((N + 31) / 32), dim3(B), 0, stream, x, W1, h0, N);

    hipLaunchKernelGGL(k_agg96, dim3((N * 24 + B - 1) / B), dim3(B), 0, stream,
                       h0, off, epk, dinv, b1, h, N);

    hipLaunchKernelGGL(k_gemm2, dim3((N + 63) / 64), dim3(B), 0, stream, h, W2, h1, N);

    hipLaunchKernelGGL(k_agg40, dim3((N * 10 + B - 1) / B), dim3(B), 0, stream,
                       h1, off, epk, dinv, b2, out, N);

    hipLaunchKernelGGL(k_lsm, dim3((N * 64 + B - 1) / B), dim3(B), 0, stream, out, N);
}

// Round 3
// 286.150 us; speedup vs baseline: 2.0871x; 1.2041x over previous
//
#include <hip/hip_runtime.h>
#include <hip/hip_bf16.h>
#include <math.h>

#define NN 50000
#define EE 800000
#define FIN 256
#define FH 96
#define FC 40

// ---------------- init: deg=1 (self loop), cnt=0 ----------------

__global__ void k_init(unsigned* __restrict__ deg, unsigned* __restrict__ cnt, int n) {
    int i = blockIdx.x * blockDim.x + threadIdx.x;
    if (i < n) { deg[i] = 1u; cnt[i] = 0u; }
}

// ---------------- count out-degree (row) and in-count (col) ----------------

__global__ void k_count(const int* __restrict__ row, const int* __restrict__ col,
                        unsigned* __restrict__ deg, unsigned* __restrict__ cnt, int e) {
    int i = blockIdx.x * blockDim.x + threadIdx.x;
    if (i < e) {
        atomicAdd(&deg[row[i]], 1u);
        atomicAdd(&cnt[col[i]], 1u);
    }
}

__global__ void k_dinv(unsigned* deg, int n) {
    int i = blockIdx.x * blockDim.x + threadIdx.x;
    if (i < n) {
        unsigned d = deg[i];
        ((float*)deg)[i] = rsqrtf((float)d);
    }
}

// ---------------- exclusive scan of cnt -> off ----------------

__global__ __launch_bounds__(1024) void k_scanA(const unsigned* __restrict__ cnt,
                                                unsigned* __restrict__ off,
                                                unsigned* __restrict__ bsum, int n) {
    __shared__ unsigned s[1024];
    int t = threadIdx.x;
    int i = blockIdx.x * 1024 + t;
    unsigned v = (i < n) ? cnt[i] : 0u;
    s[t] = v;
    __syncthreads();
    for (int o = 1; o < 1024; o <<= 1) {
        unsigned tv = (t >= o) ? s[t - o] : 0u;
        __syncthreads();
        s[t] += tv;
        __syncthreads();
    }
    if (i < n) off[i] = s[t] - v;  // exclusive
    if (t == 1023) bsum[blockIdx.x] = s[1023];
}

__global__ void k_scanB1(unsigned* bsum, int nb) {
    if (threadIdx.x == 0 && blockIdx.x == 0) {
        unsigned run = 0;
        for (int b = 0; b < nb; ++b) { unsigned tv = bsum[b]; bsum[b] = run; run += tv; }
    }
}

__global__ void k_scanB2(unsigned* __restrict__ off, const unsigned* __restrict__ bsum,
                         unsigned* __restrict__ cursor, int n, unsigned e) {
    int i = blockIdx.x * blockDim.x + threadIdx.x;
    if (i < n) {
        unsigned v = off[i] + bsum[i >> 10];
        off[i] = v;
        cursor[i] = v;
    }
    if (i == n) off[n] = e;
}

// ---------------- bucket-scatter edges into CSR (packed {row, norm}) ----------------

__global__ void k_csr(const int* __restrict__ row, const int* __restrict__ col,
                      const float* __restrict__ ew, const float* __restrict__ dinv,
                      unsigned* __restrict__ cursor, float2* __restrict__ epk, int e) {
    int i = blockIdx.x * blockDim.x + threadIdx.x;
    if (i >= e) return;
    int r = row[i], c = col[i];
    unsigned pos = atomicAdd(&cursor[c], 1u);
    float2 p;
    p.x = __int_as_float(r);
    p.y = dinv[r] * ew[i] * dinv[c];
    epk[pos] = p;
}

// ---------------- GEMM1: h0 = x @ W1^T  [N,256]x[96,256]^T -> [N,96] ----------------
// 128x96 block tile, thread = 4 rows x 12 cols, k-major LDS, b128 fragment reads.

__global__ __launch_bounds__(256) void k_gemm1(const float* __restrict__ x,
                                               const float* __restrict__ W,
                                               float* __restrict__ h0, int n) {
    __shared__ float xs[32][132];  // [k][row], pad 132 -> 2-way write conflict only
    __shared__ float ws[32][100];  // [k][col]
    int tid = threadIdx.x;
    int row0 = blockIdx.x * 128;
    int rg = tid & 31, cg = tid >> 5;

    float acc[4][12];
#pragma unroll
    for (int r = 0; r < 4; ++r)
#pragma unroll
        for (int c = 0; c < 12; ++c) acc[r][c] = 0.f;

    for (int k0 = 0; k0 < FIN; k0 += 32) {
        // x tile: 128 rows x 32 k = 1024 float4, 4 per thread (coalesced global)
#pragma unroll
        for (int i = 0; i < 4; ++i) {
            int f4i = tid + 256 * i;
            int gr = f4i >> 3;         // 0..127
            int kk = (f4i & 7) << 2;   // 0,4,..,28
            int grow = row0 + gr;
            float4 v = make_float4(0.f, 0.f, 0.f, 0.f);
            if (grow < n) v = *(const float4*)&x[grow * FIN + k0 + kk];
            xs[kk + 0][gr] = v.x; xs[kk + 1][gr] = v.y;
            xs[kk + 2][gr] = v.z; xs[kk + 3][gr] = v.w;
        }
        // w tile: 96 cols x 32 k = 768 float4, 3 per thread
#pragma unroll
        for (int i = 0; i < 3; ++i) {
            int f4i = tid + 256 * i;
            int wc = f4i >> 3;         // 0..95
            int kk = (f4i & 7) << 2;
            float4 v = *(const float4*)&W[wc * FIN + k0 + kk];
            ws[kk + 0][wc] = v.x; ws[kk + 1][wc] = v.y;
            ws[kk + 2][wc] = v.z; ws[kk + 3][wc] = v.w;
        }
        __syncthreads();
#pragma unroll 8
        for (int k = 0; k < 32; ++k) {
            float4 xv = *(const float4*)&xs[k][4 * rg];
            float4 w0 = *(const float4*)&ws[k][4 * cg];
            float4 w1 = *(const float4*)&ws[k][4 * cg + 32];
            float4 w2 = *(const float4*)&ws[k][4 * cg + 64];
            const float xr[4] = {xv.x, xv.y, xv.z, xv.w};
#pragma unroll
            for (int r = 0; r < 4; ++r) {
                acc[r][0]  = fmaf(xr[r], w0.x, acc[r][0]);
                acc[r][1]  = fmaf(xr[r], w0.y, acc[r][1]);
                acc[r][2]  = fmaf(xr[r], w0.z, acc[r][2]);
                acc[r][3]  = fmaf(xr[r], w0.w, acc[r][3]);
                acc[r][4]  = fmaf(xr[r], w1.x, acc[r][4]);
                acc[r][5]  = fmaf(xr[r], w1.y, acc[r][5]);
                acc[r][6]  = fmaf(xr[r], w1.z, acc[r][6]);
                acc[r][7]  = fmaf(xr[r], w1.w, acc[r][7]);
                acc[r][8]  = fmaf(xr[r], w2.x, acc[r][8]);
                acc[r][9]  = fmaf(xr[r], w2.y, acc[r][9]);
                acc[r][10] = fmaf(xr[r], w2.z, acc[r][10]);
                acc[r][11] = fmaf(xr[r], w2.w, acc[r][11]);
            }
        }
        __syncthreads();
    }
#pragma unroll
    for (int r = 0; r < 4; ++r) {
        int grow = row0 + 4 * rg + r;
        if (grow < n) {
#pragma unroll
            for (int c = 0; c < 3; ++c) {
                float4 v = make_float4(acc[r][4 * c], acc[r][4 * c + 1],
                                       acc[r][4 * c + 2], acc[r][4 * c + 3]);
                *(float4*)&h0[grow * FH + 4 * cg + 32 * c] = v;
            }
        }
    }
}

// ---------------- aggregation 96: h = relu(A_norm @ h0 + b1) ----------------

__global__ __launch_bounds__(256) void k_agg96(const float* __restrict__ h0,
                                               const unsigned* __restrict__ off,
                                               const float2* __restrict__ epk,
                                               const float* __restrict__ dinv,
                                               const float* __restrict__ b,
                                               float* __restrict__ outh, int n) {
    int tid = blockIdx.x * 256 + threadIdx.x;
    int node = tid / 24;
    int f4 = tid - node * 24;
    if (node >= n) return;
    float s = dinv[node]; s = s * s;
    float4 acc = ((const float4*)h0)[node * 24 + f4];
    acc.x *= s; acc.y *= s; acc.z *= s; acc.w *= s;
    unsigned st = off[node], en = off[node + 1];
    for (unsigned e = st; e < en; ++e) {
        float2 p = epk[e];
        int r = __float_as_int(p.x);
        float nr = p.y;
        float4 v = ((const float4*)h0)[r * 24 + f4];
        acc.x = fmaf(nr, v.x, acc.x);
        acc.y = fmaf(nr, v.y, acc.y);
        acc.z = fmaf(nr, v.z, acc.z);
        acc.w = fmaf(nr, v.w, acc.w);
    }
    float4 bv = ((const float4*)b)[f4];
    acc.x = fmaxf(acc.x + bv.x, 0.f);
    acc.y = fmaxf(acc.y + bv.y, 0.f);
    acc.z = fmaxf(acc.z + bv.z, 0.f);
    acc.w = fmaxf(acc.w + bv.w, 0.f);
    ((float4*)outh)[node * 24 + f4] = acc;
}

// ---------------- GEMM2: h1 = h @ W2^T  [N,96]x[40,96]^T -> [N,40] ----------------
// 128x40 block tile, thread = 4 rows x 5 cols, KT=48.

__global__ __launch_bounds__(256) void k_gemm2(const float* __restrict__ h,
                                               const float* __restrict__ W,
                                               float* __restrict__ h1, int n) {
    __shared__ float hs[48][132];  // [k][row]
    __shared__ float w2s[48][44];  // [k][col]
    int tid = threadIdx.x;
    int row0 = blockIdx.x * 128;
    int rg = tid & 31, cg = tid >> 5;

    float acc[4][5];
#pragma unroll
    for (int r = 0; r < 4; ++r)
#pragma unroll
        for (int c = 0; c < 5; ++c) acc[r][c] = 0.f;

    for (int k0 = 0; k0 < FH; k0 += 48) {
        // h tile: 128 rows x 48 k = 1536 float4, 6 per thread
#pragma unroll
        for (int i = 0; i < 6; ++i) {
            int f4i = tid + 256 * i;
            int gr = f4i / 12;            // 0..127
            int kk = (f4i - gr * 12) << 2;
            int grow = row0 + gr;
            float4 v = make_float4(0.f, 0.f, 0.f, 0.f);
            if (grow < n) v = *(const float4*)&h[grow * FH + k0 + kk];
            hs[kk + 0][gr] = v.x; hs[kk + 1][gr] = v.y;
            hs[kk + 2][gr] = v.z; hs[kk + 3][gr] = v.w;
        }
        // w tile: 40 cols x 48 k = 480 float4, 2 per thread (with guard)
#pragma unroll
        for (int i = 0; i < 2; ++i) {
            int f4i = tid + 256 * i;
            if (f4i < 480) {
                int wc = f4i / 12;
                int kk = (f4i - wc * 12) << 2;
                float4 v = *(const float4*)&W[wc * FH + k0 + kk];
                w2s[kk + 0][wc] = v.x; w2s[kk + 1][wc] = v.y;
                w2s[kk + 2][wc] = v.z; w2s[kk + 3][wc] = v.w;
            }
        }
        __syncthreads();
#pragma unroll 8
        for (int k = 0; k < 48; ++k) {
            float4 xv = *(const float4*)&hs[k][4 * rg];
            const float xr[4] = {xv.x, xv.y, xv.z, xv.w};
            float wv[5];
#pragma unroll
            for (int c = 0; c < 5; ++c) wv[c] = w2s[k][5 * cg + c];
#pragma unroll
            for (int r = 0; r < 4; ++r)
#pragma unroll
                for (int c = 0; c < 5; ++c)
                    acc[r][c] = fmaf(xr[r], wv[c], acc[r][c]);
        }
        __syncthreads();
    }
#pragma unroll
    for (int r = 0; r < 4; ++r) {
        int grow = row0 + 4 * rg + r;
        if (grow < n) {
#pragma unroll
            for (int c = 0; c < 5; ++c) h1[grow * FC + 5 * cg + c] = acc[r][c];
        }
    }
}

// ---------------- aggregation 40: out = A_norm @ h1 + b2 ----------------

__global__ __launch_bounds__(256) void k_agg40(const float* __restrict__ h1,
                                               const unsigned* __restrict__ off,
                                               const float2* __restrict__ epk,
                                               const float* __restrict__ dinv,
                                               const float* __restrict__ b,
                                               float* __restrict__ out, int n) {
    int tid = blockIdx.x * 256 + threadIdx.x;
    int node = tid / 10;
    int f4 = tid - node * 10;
    if (node >= n) return;
    float s = dinv[node]; s = s * s;
    float4 acc = ((const float4*)h1)[node * 10 + f4];
    acc.x *= s; acc.y *= s; acc.z *= s; acc.w *= s;
    unsigned st = off[node], en = off[node + 1];
    for (unsigned e = st; e < en; ++e) {
        float2 p = epk[e];
        int r = __float_as_int(p.x);
        float nr = p.y;
        float4 v = ((const float4*)h1)[r * 10 + f4];
        acc.x = fmaf(nr, v.x, acc.x);
        acc.y = fmaf(nr, v.y, acc.y);
        acc.z = fmaf(nr, v.z, acc.z);
        acc.w = fmaf(nr, v.w, acc.w);
    }
    float4 bv = ((const float4*)b)[f4];
    acc.x += bv.x; acc.y += bv.y; acc.z += bv.z; acc.w += bv.w;
    ((float4*)out)[node * 10 + f4] = acc;
}

// ---------------- log_softmax (wave per row) ----------------

__global__ void k_lsm(float* __restrict__ out, int n) {
    int gtid = blockIdx.x * blockDim.x + threadIdx.x;
    int wid = gtid >> 6;
    int lane = threadIdx.x & 63;
    if (wid >= n) return;
    float vv = 0.f, v = -INFINITY;
    if (lane < FC) {
        vv = out[wid * FC + lane];
        v = vv;
    }
#pragma unroll
    for (int o = 32; o; o >>= 1) v = fmaxf(v, __shfl_xor(v, o));
    float ex = (lane < FC) ? expf(vv - v) : 0.f;
#pragma unroll
    for (int o = 32; o; o >>= 1) ex += __shfl_xor(ex, o);
    float lse = logf(ex) + v;
    if (lane < FC) out[wid * FC + lane] = vv - lse;
}

// ---------------- launch ----------------

extern "C" void kernel_launch(void* const* d_in, const int* in_sizes, int n_in,
                              void* d_out, int out_size, void* d_ws, size_t ws_size,
                              hipStream_t stream) {
    const float* x  = (const float*)d_in[0];
    const int*   ei = (const int*)d_in[1];
    const float* ew = (const float*)d_in[2];
    const float* W1 = (const float*)d_in[3];
    const float* b1 = (const float*)d_in[4];
    const float* W2 = (const float*)d_in[5];
    const float* b2 = (const float*)d_in[6];
    float* out = (float*)d_out;

    const int N = NN;
    const int E = in_sizes[1] / 2;
    const int* row = ei;
    const int* col = ei + E;

    float* ws = (float*)d_ws;
    unsigned* deg    = (unsigned*)(ws + 0);        // N (becomes dinv)
    float*    dinv   = (float*)deg;
    unsigned* cnt    = (unsigned*)(ws + 50176);    // N (becomes cursor)
    unsigned* cursor = cnt;
    unsigned* off    = (unsigned*)(ws + 100352);   // N+1
    unsigned* bsum   = (unsigned*)(ws + 150656);   // 64
    float2*   epk    = (float2*)(ws + 150784);     // 2*E floats
    float*    h0     = ws + 1750784;               // N*96 (later reused as h1)
    float*    h1     = h0;
    float*    h      = ws + 6550784;               // N*96

    const int B = 256;
    const int NB_SCAN = (N + 1023) / 1024;

    hipLaunchKernelGGL(k_init, dim3((N + B - 1) / B), dim3(B), 0, stream, deg, cnt, N);
    hipLaunchKernelGGL(k_count, dim3((E + B - 1) / B), dim3(B), 0, stream, row, col, deg, cnt, E);
    hipLaunchKernelGGL(k_dinv, dim3((N + B - 1) / B), dim3(B), 0, stream, deg, N);

    hipLaunchKernelGGL(k_scanA, dim3(NB_SCAN), dim3(1024), 0, stream, cnt, off, bsum, N);
    hipLaunchKernelGGL(k_scanB1, dim3(1), dim3(64), 0, stream, bsum, NB_SCAN);
    hipLaunchKernelGGL(k_scanB2, dim3((N + 1 + B - 1) / B), dim3(B), 0, stream, off, bsum, cursor, N, (unsigned)E);

    hipLaunchKernelGGL(k_csr, dim3((E + B - 1) / B), dim3(B), 0, stream, row, col, ew, dinv, cursor, epk, E);

    hipLaunchKernelGGL(k_gemm1, dim3((N + 127) / 128), dim3(B), 0, stream, x, W1, h0, N);

    hipLaunchKernelGGL(k_agg96, dim3((N * 24 + B - 1) / B), dim3(B), 0, stream,
                       h0, off, epk, dinv, b1, h, N);

    hipLaunchKernelGGL(k_gemm2, dim3((N + 127) / 128), dim3(B), 0, stream, h, W2, h1, N);

    hipLaunchKernelGGL(k_agg40, dim3((N * 10 + B - 1) / B), dim3(B), 0, stream,
                       h1, off, epk, dinv, b2, out, N);

    hipLaunchKernelGGL(k_lsm, dim3((N * 64 + B - 1) / B), dim3(B), 0, stream, out, N);
}

// Round 4
// 250.792 us; speedup vs baseline: 2.3813x; 1.1410x over previous
//
#include <hip/hip_runtime.h>
#include <hip/hip_bf16.h>
#include <math.h>

#define NN 50000
#define EE 800000
#define FIN 256
#define FH 96
#define FC 40

// ---------------- privatized LDS histogram ----------------
// 256 blocks: {64 edge-slices} x {2 node-halves} x {row,col}.
// 16-bit packed bins, 25000 nodes/half -> 12500 u32 words = 50 KB LDS.
// Slice <= ceil(E/64) = 12500 edges -> bins can never overflow 16 bits.

__global__ __launch_bounds__(256) void k_hist(const int* __restrict__ ei, int E,
                                              unsigned* __restrict__ copies) {
    __shared__ unsigned hist[12500];
    int b = blockIdx.x;
    int slice = b & 63;
    int half = (b >> 6) & 1;
    int arr = b >> 7;
    const int* ptr = ei + (size_t)arr * E;  // arr=0: row, arr=1: col
    int tid = threadIdx.x;
    for (int i = tid; i < 12500; i += 256) hist[i] = 0u;
    __syncthreads();
    int ES = (E + 63) >> 6;
    int lo = slice * ES, hi = min(lo + ES, E);
    int nlo = half * 25000;
    for (int i = lo + tid; i < hi; i += 256) {
        int rel = ptr[i] - nlo;
        if ((unsigned)rel < 25000u)
            atomicAdd(&hist[rel >> 1], 1u << ((rel & 1) << 4));
    }
    __syncthreads();
    unsigned* dst = copies + (size_t)((arr * 2 + half) * 64 + slice) * 12500;
    for (int i = tid; i < 12500; i += 256) dst[i] = hist[i];
}

// sum the 64 copies -> dinv (float, rsqrt(deg+1)) and cnt (u32)
__global__ void k_reduce(const unsigned* __restrict__ copies,
                         float* __restrict__ dinv, unsigned* __restrict__ cnt) {
    int t = blockIdx.x * blockDim.x + threadIdx.x;  // 0..24999
    if (t >= 25000) return;
    int half = t / 12500, w = t - half * 12500;
    unsigned sr = 0, sc = 0;
    const unsigned* br = copies + (size_t)(half) * 64 * 12500 + w;      // rows
    const unsigned* bc = copies + (size_t)(2 + half) * 64 * 12500 + w;  // cols
#pragma unroll 8
    for (int s = 0; s < 64; ++s) { sr += br[s * 12500]; sc += bc[s * 12500]; }
    int n0 = half * 25000 + 2 * w;
    dinv[n0]     = rsqrtf((float)((sr & 0xffffu) + 1u));
    dinv[n0 + 1] = rsqrtf((float)((sr >> 16) + 1u));
    cnt[n0]     = sc & 0xffffu;
    cnt[n0 + 1] = sc >> 16;
}

// ---------------- exclusive scan of cnt -> off ----------------

__global__ __launch_bounds__(1024) void k_scanA(const unsigned* __restrict__ cnt,
                                                unsigned* __restrict__ off,
                                                unsigned* __restrict__ bsum, int n) {
    __shared__ unsigned s[1024];
    int t = threadIdx.x;
    int i = blockIdx.x * 1024 + t;
    unsigned v = (i < n) ? cnt[i] : 0u;
    s[t] = v;
    __syncthreads();
    for (int o = 1; o < 1024; o <<= 1) {
        unsigned tv = (t >= o) ? s[t - o] : 0u;
        __syncthreads();
        s[t] += tv;
        __syncthreads();
    }
    if (i < n) off[i] = s[t] - v;  // exclusive
    if (t == 1023) bsum[blockIdx.x] = s[1023];
}

__global__ void k_scanB1(unsigned* bsum, int nb) {
    if (threadIdx.x == 0 && blockIdx.x == 0) {
        unsigned run = 0;
        for (int b = 0; b < nb; ++b) { unsigned tv = bsum[b]; bsum[b] = run; run += tv; }
    }
}

__global__ void k_scanB2(unsigned* __restrict__ off, const unsigned* __restrict__ bsum,
                         unsigned* __restrict__ cursor, int n, unsigned e) {
    int i = blockIdx.x * blockDim.x + threadIdx.x;
    if (i < n) {
        unsigned v = off[i] + bsum[i >> 10];
        off[i] = v;
        cursor[i] = v;
    }
    if (i == n) off[n] = e;
}

// ---------------- bucket-scatter edges into CSR (packed {row, ew}) ----------------
// dinv factored out: payload no longer needs norm.

__global__ void k_csr(const int* __restrict__ row, const int* __restrict__ col,
                      const float* __restrict__ ew,
                      unsigned* __restrict__ cursor, float2* __restrict__ epk, int e) {
    int i = blockIdx.x * blockDim.x + threadIdx.x;
    if (i >= e) return;
    int r = row[i], c = col[i];
    unsigned pos = atomicAdd(&cursor[c], 1u);
    float2 p;
    p.x = __int_as_float(r);
    p.y = ew[i];
    epk[pos] = p;
}

// ---------------- GEMM1: g0 = dinv ⊙ (x @ W1^T)  [N,256]x[96,256]^T -> [N,96] ----------------

__global__ __launch_bounds__(256) void k_gemm1(const float* __restrict__ x,
                                               const float* __restrict__ W,
                                               const float* __restrict__ dinv,
                                               float* __restrict__ g0, int n) {
    __shared__ float xs[32][132];
    __shared__ float ws[32][100];
    int tid = threadIdx.x;
    int row0 = blockIdx.x * 128;
    int rg = tid & 31, cg = tid >> 5;

    float acc[4][12];
#pragma unroll
    for (int r = 0; r < 4; ++r)
#pragma unroll
        for (int c = 0; c < 12; ++c) acc[r][c] = 0.f;

    for (int k0 = 0; k0 < FIN; k0 += 32) {
#pragma unroll
        for (int i = 0; i < 4; ++i) {
            int f4i = tid + 256 * i;
            int gr = f4i >> 3;
            int kk = (f4i & 7) << 2;
            int grow = row0 + gr;
            float4 v = make_float4(0.f, 0.f, 0.f, 0.f);
            if (grow < n) v = *(const float4*)&x[grow * FIN + k0 + kk];
            xs[kk + 0][gr] = v.x; xs[kk + 1][gr] = v.y;
            xs[kk + 2][gr] = v.z; xs[kk + 3][gr] = v.w;
        }
#pragma unroll
        for (int i = 0; i < 3; ++i) {
            int f4i = tid + 256 * i;
            int wc = f4i >> 3;
            int kk = (f4i & 7) << 2;
            float4 v = *(const float4*)&W[wc * FIN + k0 + kk];
            ws[kk + 0][wc] = v.x; ws[kk + 1][wc] = v.y;
            ws[kk + 2][wc] = v.z; ws[kk + 3][wc] = v.w;
        }
        __syncthreads();
#pragma unroll 8
        for (int k = 0; k < 32; ++k) {
            float4 xv = *(const float4*)&xs[k][4 * rg];
            float4 w0 = *(const float4*)&ws[k][4 * cg];
            float4 w1 = *(const float4*)&ws[k][4 * cg + 32];
            float4 w2 = *(const float4*)&ws[k][4 * cg + 64];
            const float xr[4] = {xv.x, xv.y, xv.z, xv.w};
#pragma unroll
            for (int r = 0; r < 4; ++r) {
                acc[r][0]  = fmaf(xr[r], w0.x, acc[r][0]);
                acc[r][1]  = fmaf(xr[r], w0.y, acc[r][1]);
                acc[r][2]  = fmaf(xr[r], w0.z, acc[r][2]);
                acc[r][3]  = fmaf(xr[r], w0.w, acc[r][3]);
                acc[r][4]  = fmaf(xr[r], w1.x, acc[r][4]);
                acc[r][5]  = fmaf(xr[r], w1.y, acc[r][5]);
                acc[r][6]  = fmaf(xr[r], w1.z, acc[r][6]);
                acc[r][7]  = fmaf(xr[r], w1.w, acc[r][7]);
                acc[r][8]  = fmaf(xr[r], w2.x, acc[r][8]);
                acc[r][9]  = fmaf(xr[r], w2.y, acc[r][9]);
                acc[r][10] = fmaf(xr[r], w2.z, acc[r][10]);
                acc[r][11] = fmaf(xr[r], w2.w, acc[r][11]);
            }
        }
        __syncthreads();
    }
#pragma unroll
    for (int r = 0; r < 4; ++r) {
        int grow = row0 + 4 * rg + r;
        if (grow < n) {
            float dv = dinv[grow];
#pragma unroll
            for (int c = 0; c < 3; ++c) {
                float4 v = make_float4(dv * acc[r][4 * c], dv * acc[r][4 * c + 1],
                                       dv * acc[r][4 * c + 2], dv * acc[r][4 * c + 3]);
                *(float4*)&g0[grow * FH + 4 * cg + 32 * c] = v;
            }
        }
    }
}

// ---------------- aggregation 96: h = relu(dinv[c]*(g0[c] + Σ ew*g0[r]) + b1) ----------------

__global__ __launch_bounds__(256) void k_agg96(const float* __restrict__ g0,
                                               const unsigned* __restrict__ off,
                                               const float2* __restrict__ epk,
                                               const float* __restrict__ dinv,
                                               const float* __restrict__ b,
                                               float* __restrict__ outh, int n) {
    int tid = blockIdx.x * 256 + threadIdx.x;
    int node = tid / 24;
    int f4 = tid - node * 24;
    if (node >= n) return;
    float4 acc = ((const float4*)g0)[node * 24 + f4];
    unsigned st = off[node], en = off[node + 1];
    for (unsigned e = st; e < en; ++e) {
        float2 p = epk[e];
        int r = __float_as_int(p.x);
        float wv = p.y;
        float4 v = ((const float4*)g0)[r * 24 + f4];
        acc.x = fmaf(wv, v.x, acc.x);
        acc.y = fmaf(wv, v.y, acc.y);
        acc.z = fmaf(wv, v.z, acc.z);
        acc.w = fmaf(wv, v.w, acc.w);
    }
    float s = dinv[node];
    float4 bv = ((const float4*)b)[f4];
    acc.x = fmaxf(fmaf(s, acc.x, bv.x), 0.f);
    acc.y = fmaxf(fmaf(s, acc.y, bv.y), 0.f);
    acc.z = fmaxf(fmaf(s, acc.z, bv.z), 0.f);
    acc.w = fmaxf(fmaf(s, acc.w, bv.w), 0.f);
    ((float4*)outh)[node * 24 + f4] = acc;
}

// ---------------- GEMM2: g1 = dinv ⊙ (h @ W2^T)  [N,96]x[40,96]^T -> [N,40] ----------------

__global__ __launch_bounds__(256) void k_gemm2(const float* __restrict__ h,
                                               const float* __restrict__ W,
                                               const float* __restrict__ dinv,
                                               float* __restrict__ g1, int n) {
    __shared__ float hs[48][132];
    __shared__ float w2s[48][44];
    int tid = threadIdx.x;
    int row0 = blockIdx.x * 128;
    int rg = tid & 31, cg = tid >> 5;

    float acc[4][5];
#pragma unroll
    for (int r = 0; r < 4; ++r)
#pragma unroll
        for (int c = 0; c < 5; ++c) acc[r][c] = 0.f;

    for (int k0 = 0; k0 < FH; k0 += 48) {
#pragma unroll
        for (int i = 0; i < 6; ++i) {
            int f4i = tid + 256 * i;
            int gr = f4i / 12;
            int kk = (f4i - gr * 12) << 2;
            int grow = row0 + gr;
            float4 v = make_float4(0.f, 0.f, 0.f, 0.f);
            if (grow < n) v = *(const float4*)&h[grow * FH + k0 + kk];
            hs[kk + 0][gr] = v.x; hs[kk + 1][gr] = v.y;
            hs[kk + 2][gr] = v.z; hs[kk + 3][gr] = v.w;
        }
#pragma unroll
        for (int i = 0; i < 2; ++i) {
            int f4i = tid + 256 * i;
            if (f4i < 480) {
                int wc = f4i / 12;
                int kk = (f4i - wc * 12) << 2;
                float4 v = *(const float4*)&W[wc * FH + k0 + kk];
                w2s[kk + 0][wc] = v.x; w2s[kk + 1][wc] = v.y;
                w2s[kk + 2][wc] = v.z; w2s[kk + 3][wc] = v.w;
            }
        }
        __syncthreads();
#pragma unroll 8
        for (int k = 0; k < 48; ++k) {
            float4 xv = *(const float4*)&hs[k][4 * rg];
            const float xr[4] = {xv.x, xv.y, xv.z, xv.w};
            float wv[5];
#pragma unroll
            for (int c = 0; c < 5; ++c) wv[c] = w2s[k][5 * cg + c];
#pragma unroll
            for (int r = 0; r < 4; ++r)
#pragma unroll
                for (int c = 0; c < 5; ++c)
                    acc[r][c] = fmaf(xr[r], wv[c], acc[r][c]);
        }
        __syncthreads();
    }
#pragma unroll
    for (int r = 0; r < 4; ++r) {
        int grow = row0 + 4 * rg + r;
        if (grow < n) {
            float dv = dinv[grow];
#pragma unroll
            for (int c = 0; c < 5; ++c) g1[grow * FC + 5 * cg + c] = dv * acc[r][c];
        }
    }
}

// ---------------- aggregation 40: out = dinv[c]*(g1[c] + Σ ew*g1[r]) + b2 ----------------

__global__ __launch_bounds__(256) void k_agg40(const float* __restrict__ g1,
                                               const unsigned* __restrict__ off,
                                               const float2* __restrict__ epk,
                                               const float* __restrict__ dinv,
                                               const float* __restrict__ b,
                                               float* __restrict__ out, int n) {
    int tid = blockIdx.x * 256 + threadIdx.x;
    int node = tid / 10;
    int f4 = tid - node * 10;
    if (node >= n) return;
    float4 acc = ((const float4*)g1)[node * 10 + f4];
    unsigned st = off[node], en = off[node + 1];
    for (unsigned e = st; e < en; ++e) {
        float2 p = epk[e];
        int r = __float_as_int(p.x);
        float wv = p.y;
        float4 v = ((const float4*)g1)[r * 10 + f4];
        acc.x = fmaf(wv, v.x, acc.x);
        acc.y = fmaf(wv, v.y, acc.y);
        acc.z = fmaf(wv, v.z, acc.z);
        acc.w = fmaf(wv, v.w, acc.w);
    }
    float s = dinv[node];
    float4 bv = ((const float4*)b)[f4];
    acc.x = fmaf(s, acc.x, bv.x);
    acc.y = fmaf(s, acc.y, bv.y);
    acc.z = fmaf(s, acc.z, bv.z);
    acc.w = fmaf(s, acc.w, bv.w);
    ((float4*)out)[node * 10 + f4] = acc;
}

// ---------------- log_softmax (wave per row) ----------------

__global__ void k_lsm(float* __restrict__ out, int n) {
    int gtid = blockIdx.x * blockDim.x + threadIdx.x;
    int wid = gtid >> 6;
    int lane = threadIdx.x & 63;
    if (wid >= n) return;
    float vv = 0.f, v = -INFINITY;
    if (lane < FC) {
        vv = out[wid * FC + lane];
        v = vv;
    }
#pragma unroll
    for (int o = 32; o; o >>= 1) v = fmaxf(v, __shfl_xor(v, o));
    float ex = (lane < FC) ? expf(vv - v) : 0.f;
#pragma unroll
    for (int o = 32; o; o >>= 1) ex += __shfl_xor(ex, o);
    float lse = logf(ex) + v;
    if (lane < FC) out[wid * FC + lane] = vv - lse;
}

// ---------------- launch ----------------

extern "C" void kernel_launch(void* const* d_in, const int* in_sizes, int n_in,
                              void* d_out, int out_size, void* d_ws, size_t ws_size,
                              hipStream_t stream) {
    const float* x  = (const float*)d_in[0];
    const int*   ei = (const int*)d_in[1];
    const float* ew = (const float*)d_in[2];
    const float* W1 = (const float*)d_in[3];
    const float* b1 = (const float*)d_in[4];
    const float* W2 = (const float*)d_in[5];
    const float* b2 = (const float*)d_in[6];
    float* out = (float*)d_out;

    const int N = NN;
    const int E = in_sizes[1] / 2;
    const int* row = ei;
    const int* col = ei + E;

    float* ws = (float*)d_ws;
    // workspace layout (4-byte units); total 11,350,784 words = 45.4 MB
    float*    dinv   = (float*)(ws + 0);           // N
    unsigned* cnt    = (unsigned*)(ws + 50176);    // N (becomes cursor)
    unsigned* cursor = cnt;
    unsigned* off    = (unsigned*)(ws + 100352);   // N+1
    unsigned* bsum   = (unsigned*)(ws + 150656);   // 128
    unsigned* copies = (unsigned*)(ws + 150784);   // 4*64*12500 = 3.2M (dead after k_reduce)
    float2*   epk    = (float2*)(ws + 150784);     // 2*E floats (overlaps copies, written later)
    float*    h      = ws + 1750784;               // N*96 (overlaps copies tail, written later)
    float*    g0     = ws + 6550784;               // N*96 (reused as g1)
    float*    g1     = g0;

    const int B = 256;
    const int NB_SCAN = (N + 1023) / 1024;

    hipLaunchKernelGGL(k_hist, dim3(256), dim3(B), 0, stream, ei, E, copies);
    hipLaunchKernelGGL(k_reduce, dim3((25000 + B - 1) / B), dim3(B), 0, stream, copies, dinv, cnt);

    hipLaunchKernelGGL(k_scanA, dim3(NB_SCAN), dim3(1024), 0, stream, cnt, off, bsum, N);
    hipLaunchKernelGGL(k_scanB1, dim3(1), dim3(64), 0, stream, bsum, NB_SCAN);
    hipLaunchKernelGGL(k_scanB2, dim3((N + 1 + B - 1) / B), dim3(B), 0, stream, off, bsum, cursor, N, (unsigned)E);

    hipLaunchKernelGGL(k_csr, dim3((E + B - 1) / B), dim3(B), 0, stream, row, col, ew, cursor, epk, E);

    hipLaunchKernelGGL(k_gemm1, dim3((N + 127) / 128), dim3(B), 0, stream, x, W1, dinv, g0, N);

    hipLaunchKernelGGL(k_agg96, dim3((N * 24 + B - 1) / B), dim3(B), 0, stream,
                       g0, off, epk, dinv, b1, h, N);

    hipLaunchKernelGGL(k_gemm2, dim3((N + 127) / 128), dim3(B), 0, stream, h, W2, dinv, g1, N);

    hipLaunchKernelGGL(k_agg40, dim3((N * 10 + B - 1) / B), dim3(B), 0, stream,
                       g1, off, epk, dinv, b2, out, N);

    hipLaunchKernelGGL(k_lsm, dim3((N * 64 + B - 1) / B), dim3(B), 0, stream, out, N);
}

// Round 5
// 227.231 us; speedup vs baseline: 2.6282x; 1.1037x over previous
//
#include <hip/hip_runtime.h>
#include <hip/hip_bf16.h>
#include <math.h>

#define NN 50000
#define EE 800000
#define FIN 256
#define FH 96
#define FC 40
#define NBK 196   // ceil(50000/256) buckets of 256 nodes

// ---------------- privatized LDS histogram (deg by row, cnt by col) ----------------

__global__ __launch_bounds__(256) void k_hist(const int* __restrict__ ei, int E,
                                              unsigned* __restrict__ copies) {
    __shared__ unsigned hist[12500];
    int b = blockIdx.x;
    int slice = b & 63;
    int half = (b >> 6) & 1;
    int arr = b >> 7;
    const int* ptr = ei + (size_t)arr * E;  // arr=0: row, arr=1: col
    int tid = threadIdx.x;
    for (int i = tid; i < 12500; i += 256) hist[i] = 0u;
    __syncthreads();
    int ES = (E + 63) >> 6;
    int lo = slice * ES, hi = min(lo + ES, E);
    int nlo = half * 25000;
    for (int i = lo + tid; i < hi; i += 256) {
        int rel = ptr[i] - nlo;
        if ((unsigned)rel < 25000u)
            atomicAdd(&hist[rel >> 1], 1u << ((rel & 1) << 4));
    }
    __syncthreads();
    unsigned* dst = copies + (size_t)((arr * 2 + half) * 64 + slice) * 12500;
    for (int i = tid; i < 12500; i += 256) dst[i] = hist[i];
}

// sum the 64 copies -> dinv (float, rsqrt(deg+1)) and cnt (u32)
__global__ void k_reduce(const unsigned* __restrict__ copies,
                         float* __restrict__ dinv, unsigned* __restrict__ cnt) {
    int t = blockIdx.x * blockDim.x + threadIdx.x;  // 0..24999
    if (t >= 25000) return;
    int half = t / 12500, w = t - half * 12500;
    unsigned sr = 0, sc = 0;
    const unsigned* br = copies + (size_t)(half) * 64 * 12500 + w;      // rows
    const unsigned* bc = copies + (size_t)(2 + half) * 64 * 12500 + w;  // cols
#pragma unroll 8
    for (int s = 0; s < 64; ++s) { sr += br[s * 12500]; sc += bc[s * 12500]; }
    int n0 = half * 25000 + 2 * w;
    dinv[n0]     = rsqrtf((float)((sr & 0xffffu) + 1u));
    dinv[n0 + 1] = rsqrtf((float)((sr >> 16) + 1u));
    cnt[n0]     = sc & 0xffffu;
    cnt[n0 + 1] = sc >> 16;
}

// ---------------- exclusive scan of cnt -> off ----------------

__global__ __launch_bounds__(1024) void k_scanA(const unsigned* __restrict__ cnt,
                                                unsigned* __restrict__ off,
                                                unsigned* __restrict__ bsum, int n) {
    __shared__ unsigned s[1024];
    int t = threadIdx.x;
    int i = blockIdx.x * 1024 + t;
    unsigned v = (i < n) ? cnt[i] : 0u;
    s[t] = v;
    __syncthreads();
    for (int o = 1; o < 1024; o <<= 1) {
        unsigned tv = (t >= o) ? s[t - o] : 0u;
        __syncthreads();
        s[t] += tv;
        __syncthreads();
    }
    if (i < n) off[i] = s[t] - v;  // exclusive
    if (t == 1023) bsum[blockIdx.x] = s[1023];
}

__global__ void k_scanB1(unsigned* bsum, int nb) {
    if (threadIdx.x == 0 && blockIdx.x == 0) {
        unsigned run = 0;
        for (int b = 0; b < nb; ++b) { unsigned tv = bsum[b]; bsum[b] = run; run += tv; }
    }
}

__global__ void k_scanB2(unsigned* __restrict__ off, const unsigned* __restrict__ bsum,
                         int n, unsigned e) {
    int i = blockIdx.x * blockDim.x + threadIdx.x;
    if (i < n) off[i] = off[i] + bsum[i >> 10];
    if (i == n) off[n] = e;
}

// gcur[b] = off[b*256]
__global__ void k_initgc(const unsigned* __restrict__ off, unsigned* __restrict__ gcur) {
    int b = threadIdx.x + blockIdx.x * blockDim.x;
    if (b < NBK) gcur[b] = off[b * 256];
}

// ---------------- P1: coarse bucket by col>>8 (count, reserve, place) ----------------

__global__ __launch_bounds__(256) void k_bucket(const int* __restrict__ row,
                                                const int* __restrict__ col,
                                                const float* __restrict__ ew,
                                                unsigned* __restrict__ gcur,
                                                unsigned* __restrict__ bkc,
                                                float2* __restrict__ bkrw, int E) {
    __shared__ unsigned cnt[NBK];
    __shared__ unsigned cur[NBK];
    int tid = threadIdx.x;
    int CH = (E + gridDim.x - 1) / gridDim.x;
    int lo = blockIdx.x * CH, hi = min(lo + CH, E);
    for (int i = tid; i < NBK; i += 256) cnt[i] = 0u;
    __syncthreads();
    for (int i = lo + tid; i < hi; i += 256) atomicAdd(&cnt[col[i] >> 8], 1u);
    __syncthreads();
    for (int i = tid; i < NBK; i += 256) cur[i] = atomicAdd(&gcur[i], cnt[i]);
    __syncthreads();
    for (int i = lo + tid; i < hi; i += 256) {
        int c = col[i];
        unsigned pos = atomicAdd(&cur[c >> 8], 1u);
        bkc[pos] = (unsigned)c;
        float2 p;
        p.x = __int_as_float(row[i]);
        p.y = ew[i];
        bkrw[pos] = p;
    }
}

// ---------------- P2: exact place within bucket (block = bucket, contiguous epk slice) ----------------

__global__ __launch_bounds__(256) void k_place(const unsigned* __restrict__ bkc,
                                               const float2* __restrict__ bkrw,
                                               const unsigned* __restrict__ off,
                                               float2* __restrict__ epk, int n) {
    __shared__ unsigned cur[256];
    int b = blockIdx.x;
    int tid = threadIdx.x;
    int node0 = b * 256;
    int node = node0 + tid;
    cur[tid] = off[(node <= n) ? node : n];
    __syncthreads();
    unsigned st = off[node0];
    unsigned en = off[min(node0 + 256, n)];
    for (unsigned i = st + tid; i < en; i += 256) {
        unsigned c = bkc[i];
        unsigned pos = atomicAdd(&cur[c & 255], 1u);
        epk[pos] = bkrw[i];
    }
}

// ---------------- GEMM1: g0 = dinv ⊙ (x @ W1^T) ----------------

__global__ __launch_bounds__(256) void k_gemm1(const float* __restrict__ x,
                                               const float* __restrict__ W,
                                               const float* __restrict__ dinv,
                                               float* __restrict__ g0, int n) {
    __shared__ float xs[32][132];
    __shared__ float ws[32][100];
    int tid = threadIdx.x;
    int row0 = blockIdx.x * 128;
    int rg = tid & 31, cg = tid >> 5;

    float acc[4][12];
#pragma unroll
    for (int r = 0; r < 4; ++r)
#pragma unroll
        for (int c = 0; c < 12; ++c) acc[r][c] = 0.f;

    for (int k0 = 0; k0 < FIN; k0 += 32) {
#pragma unroll
        for (int i = 0; i < 4; ++i) {
            int f4i = tid + 256 * i;
            int gr = f4i >> 3;
            int kk = (f4i & 7) << 2;
            int grow = row0 + gr;
            float4 v = make_float4(0.f, 0.f, 0.f, 0.f);
            if (grow < n) v = *(const float4*)&x[grow * FIN + k0 + kk];
            xs[kk + 0][gr] = v.x; xs[kk + 1][gr] = v.y;
            xs[kk + 2][gr] = v.z; xs[kk + 3][gr] = v.w;
        }
#pragma unroll
        for (int i = 0; i < 3; ++i) {
            int f4i = tid + 256 * i;
            int wc = f4i >> 3;
            int kk = (f4i & 7) << 2;
            float4 v = *(const float4*)&W[wc * FIN + k0 + kk];
            ws[kk + 0][wc] = v.x; ws[kk + 1][wc] = v.y;
            ws[kk + 2][wc] = v.z; ws[kk + 3][wc] = v.w;
        }
        __syncthreads();
#pragma unroll 8
        for (int k = 0; k < 32; ++k) {
            float4 xv = *(const float4*)&xs[k][4 * rg];
            float4 w0 = *(const float4*)&ws[k][4 * cg];
            float4 w1 = *(const float4*)&ws[k][4 * cg + 32];
            float4 w2 = *(const float4*)&ws[k][4 * cg + 64];
            const float xr[4] = {xv.x, xv.y, xv.z, xv.w};
#pragma unroll
            for (int r = 0; r < 4; ++r) {
                acc[r][0]  = fmaf(xr[r], w0.x, acc[r][0]);
                acc[r][1]  = fmaf(xr[r], w0.y, acc[r][1]);
                acc[r][2]  = fmaf(xr[r], w0.z, acc[r][2]);
                acc[r][3]  = fmaf(xr[r], w0.w, acc[r][3]);
                acc[r][4]  = fmaf(xr[r], w1.x, acc[r][4]);
                acc[r][5]  = fmaf(xr[r], w1.y, acc[r][5]);
                acc[r][6]  = fmaf(xr[r], w1.z, acc[r][6]);
                acc[r][7]  = fmaf(xr[r], w1.w, acc[r][7]);
                acc[r][8]  = fmaf(xr[r], w2.x, acc[r][8]);
                acc[r][9]  = fmaf(xr[r], w2.y, acc[r][9]);
                acc[r][10] = fmaf(xr[r], w2.z, acc[r][10]);
                acc[r][11] = fmaf(xr[r], w2.w, acc[r][11]);
            }
        }
        __syncthreads();
    }
#pragma unroll
    for (int r = 0; r < 4; ++r) {
        int grow = row0 + 4 * rg + r;
        if (grow < n) {
            float dv = dinv[grow];
#pragma unroll
            for (int c = 0; c < 3; ++c) {
                float4 v = make_float4(dv * acc[r][4 * c], dv * acc[r][4 * c + 1],
                                       dv * acc[r][4 * c + 2], dv * acc[r][4 * c + 3]);
                *(float4*)&g0[grow * FH + 4 * cg + 32 * c] = v;
            }
        }
    }
}

// ---------------- aggregation 96: h = relu(dinv[c]*(g0[c] + Σ ew*g0[r]) + b1) ----------------

__global__ __launch_bounds__(256) void k_agg96(const float* __restrict__ g0,
                                               const unsigned* __restrict__ off,
                                               const float2* __restrict__ epk,
                                               const float* __restrict__ dinv,
                                               const float* __restrict__ b,
                                               float* __restrict__ outh, int n) {
    int tid = blockIdx.x * 256 + threadIdx.x;
    int node = tid / 24;
    int f4 = tid - node * 24;
    if (node >= n) return;
    float4 acc = ((const float4*)g0)[node * 24 + f4];
    unsigned st = off[node], en = off[node + 1];
    for (unsigned e = st; e < en; ++e) {
        float2 p = epk[e];
        int r = __float_as_int(p.x);
        float wv = p.y;
        float4 v = ((const float4*)g0)[r * 24 + f4];
        acc.x = fmaf(wv, v.x, acc.x);
        acc.y = fmaf(wv, v.y, acc.y);
        acc.z = fmaf(wv, v.z, acc.z);
        acc.w = fmaf(wv, v.w, acc.w);
    }
    float s = dinv[node];
    float4 bv = ((const float4*)b)[f4];
    acc.x = fmaxf(fmaf(s, acc.x, bv.x), 0.f);
    acc.y = fmaxf(fmaf(s, acc.y, bv.y), 0.f);
    acc.z = fmaxf(fmaf(s, acc.z, bv.z), 0.f);
    acc.w = fmaxf(fmaf(s, acc.w, bv.w), 0.f);
    ((float4*)outh)[node * 24 + f4] = acc;
}

// ---------------- GEMM2: g1 = dinv ⊙ (h @ W2^T) ----------------

__global__ __launch_bounds__(256) void k_gemm2(const float* __restrict__ h,
                                               const float* __restrict__ W,
                                               const float* __restrict__ dinv,
                                               float* __restrict__ g1, int n) {
    __shared__ float hs[48][132];
    __shared__ float w2s[48][44];
    int tid = threadIdx.x;
    int row0 = blockIdx.x * 128;
    int rg = tid & 31, cg = tid >> 5;

    float acc[4][5];
#pragma unroll
    for (int r = 0; r < 4; ++r)
#pragma unroll
        for (int c = 0; c < 5; ++c) acc[r][c] = 0.f;

    for (int k0 = 0; k0 < FH; k0 += 48) {
#pragma unroll
        for (int i = 0; i < 6; ++i) {
            int f4i = tid + 256 * i;
            int gr = f4i / 12;
            int kk = (f4i - gr * 12) << 2;
            int grow = row0 + gr;
            float4 v = make_float4(0.f, 0.f, 0.f, 0.f);
            if (grow < n) v = *(const float4*)&h[grow * FH + k0 + kk];
            hs[kk + 0][gr] = v.x; hs[kk + 1][gr] = v.y;
            hs[kk + 2][gr] = v.z; hs[kk + 3][gr] = v.w;
        }
#pragma unroll
        for (int i = 0; i < 2; ++i) {
            int f4i = tid + 256 * i;
            if (f4i < 480) {
                int wc = f4i / 12;
                int kk = (f4i - wc * 12) << 2;
                float4 v = *(const float4*)&W[wc * FH + k0 + kk];
                w2s[kk + 0][wc] = v.x; w2s[kk + 1][wc] = v.y;
                w2s[kk + 2][wc] = v.z; w2s[kk + 3][wc] = v.w;
            }
        }
        __syncthreads();
#pragma unroll 8
        for (int k = 0; k < 48; ++k) {
            float4 xv = *(const float4*)&hs[k][4 * rg];
            const float xr[4] = {xv.x, xv.y, xv.z, xv.w};
            float wv[5];
#pragma unroll
            for (int c = 0; c < 5; ++c) wv[c] = w2s[k][5 * cg + c];
#pragma unroll
            for (int r = 0; r < 4; ++r)
#pragma unroll
                for (int c = 0; c < 5; ++c)
                    acc[r][c] = fmaf(xr[r], wv[c], acc[r][c]);
        }
        __syncthreads();
    }
#pragma unroll
    for (int r = 0; r < 4; ++r) {
        int grow = row0 + 4 * rg + r;
        if (grow < n) {
            float dv = dinv[grow];
#pragma unroll
            for (int c = 0; c < 5; ++c) g1[grow * FC + 5 * cg + c] = dv * acc[r][c];
        }
    }
}

// ---------------- aggregation 40: out = dinv[c]*(g1[c] + Σ ew*g1[r]) + b2 ----------------

__global__ __launch_bounds__(256) void k_agg40(const float* __restrict__ g1,
                                               const unsigned* __restrict__ off,
                                               const float2* __restrict__ epk,
                                               const float* __restrict__ dinv,
                                               const float* __restrict__ b,
                                               float* __restrict__ out, int n) {
    int tid = blockIdx.x * 256 + threadIdx.x;
    int node = tid / 10;
    int f4 = tid - node * 10;
    if (node >= n) return;
    float4 acc = ((const float4*)g1)[node * 10 + f4];
    unsigned st = off[node], en = off[node + 1];
    for (unsigned e = st; e < en; ++e) {
        float2 p = epk[e];
        int r = __float_as_int(p.x);
        float wv = p.y;
        float4 v = ((const float4*)g1)[r * 10 + f4];
        acc.x = fmaf(wv, v.x, acc.x);
        acc.y = fmaf(wv, v.y, acc.y);
        acc.z = fmaf(wv, v.z, acc.z);
        acc.w = fmaf(wv, v.w, acc.w);
    }
    float s = dinv[node];
    float4 bv = ((const float4*)b)[f4];
    acc.x = fmaf(s, acc.x, bv.x);
    acc.y = fmaf(s, acc.y, bv.y);
    acc.z = fmaf(s, acc.z, bv.z);
    acc.w = fmaf(s, acc.w, bv.w);
    ((float4*)out)[node * 10 + f4] = acc;
}

// ---------------- log_softmax (wave per row) ----------------

__global__ void k_lsm(float* __restrict__ out, int n) {
    int gtid = blockIdx.x * blockDim.x + threadIdx.x;
    int wid = gtid >> 6;
    int lane = threadIdx.x & 63;
    if (wid >= n) return;
    float vv = 0.f, v = -INFINITY;
    if (lane < FC) {
        vv = out[wid * FC + lane];
        v = vv;
    }
#pragma unroll
    for (int o = 32; o; o >>= 1) v = fmaxf(v, __shfl_xor(v, o));
    float ex = (lane < FC) ? expf(vv - v) : 0.f;
#pragma unroll
    for (int o = 32; o; o >>= 1) ex += __shfl_xor(ex, o);
    float lse = logf(ex) + v;
    if (lane < FC) out[wid * FC + lane] = vv - lse;
}

// ---------------- launch ----------------

extern "C" void kernel_launch(void* const* d_in, const int* in_sizes, int n_in,
                              void* d_out, int out_size, void* d_ws, size_t ws_size,
                              hipStream_t stream) {
    const float* x  = (const float*)d_in[0];
    const int*   ei = (const int*)d_in[1];
    const float* ew = (const float*)d_in[2];
    const float* W1 = (const float*)d_in[3];
    const float* b1 = (const float*)d_in[4];
    const float* W2 = (const float*)d_in[5];
    const float* b2 = (const float*)d_in[6];
    float* out = (float*)d_out;

    const int N = NN;
    const int E = in_sizes[1] / 2;
    const int* row = ei;
    const int* col = ei + E;

    float* ws = (float*)d_ws;
    // workspace layout (4-byte words); total 11,350,976 words = 45.4 MB
    // temporal overlays:
    //   copies [150976,3350976) : k_hist -> k_reduce
    //   bkc    [150976,950976), bkrw [950976,2550976) : k_bucket -> k_place (copies dead)
    //   h      [150976,4950976) : k_agg96 -> k_gemm2 (copies/bk dead)
    //   epk    [4950976,6550976): k_place -> k_agg40
    //   g0/g1  [6550976,11350976): k_gemm1 -> k_agg96; k_gemm2 -> k_agg40
    float*    dinv   = (float*)(ws + 0);           // N
    unsigned* cnt    = (unsigned*)(ws + 50176);    // N
    unsigned* off    = (unsigned*)(ws + 100352);   // N+1
    unsigned* bsum   = (unsigned*)(ws + 150656);   // 64
    unsigned* gcur   = (unsigned*)(ws + 150720);   // 196 (+pad to 150976)
    unsigned* copies = (unsigned*)(ws + 150976);   // 4*64*12500
    unsigned* bkc    = (unsigned*)(ws + 150976);   // E
    float2*   bkrw   = (float2*)(ws + 950976);     // E float2
    float*    h      = ws + 150976;                // N*96
    float2*   epk    = (float2*)(ws + 4950976);    // E float2
    float*    g0     = ws + 6550976;               // N*96 (reused as g1)
    float*    g1     = g0;

    const int B = 256;
    const int NB_SCAN = (N + 1023) / 1024;

    hipLaunchKernelGGL(k_hist, dim3(256), dim3(B), 0, stream, ei, E, copies);
    hipLaunchKernelGGL(k_reduce, dim3((25000 + B - 1) / B), dim3(B), 0, stream, copies, dinv, cnt);

    hipLaunchKernelGGL(k_scanA, dim3(NB_SCAN), dim3(1024), 0, stream, cnt, off, bsum, N);
    hipLaunchKernelGGL(k_scanB1, dim3(1), dim3(64), 0, stream, bsum, NB_SCAN);
    hipLaunchKernelGGL(k_scanB2, dim3((N + 1 + B - 1) / B), dim3(B), 0, stream, off, bsum, N, (unsigned)E);
    hipLaunchKernelGGL(k_initgc, dim3(1), dim3(B), 0, stream, off, gcur);

    hipLaunchKernelGGL(k_bucket, dim3(320), dim3(B), 0, stream, row, col, ew, gcur, bkc, bkrw, E);
    hipLaunchKernelGGL(k_place, dim3(NBK), dim3(B), 0, stream, bkc, bkrw, off, epk, N);

    hipLaunchKernelGGL(k_gemm1, dim3((N + 127) / 128), dim3(B), 0, stream, x, W1, dinv, g0, N);

    hipLaunchKernelGGL(k_agg96, dim3((N * 24 + B - 1) / B), dim3(B), 0, stream,
                       g0, off, epk, dinv, b1, h, N);

    hipLaunchKernelGGL(k_gemm2, dim3((N + 127) / 128), dim3(B), 0, stream, h, W2, dinv, g1, N);

    hipLaunchKernelGGL(k_agg40, dim3((N * 10 + B - 1) / B), dim3(B), 0, stream,
                       g1, off, epk, dinv, b2, out, N);

    hipLaunchKernelGGL(k_lsm, dim3((N * 64 + B - 1) / B), dim3(B), 0, stream, out, N);
}